// Round 1
// baseline (155.410 us; speedup 1.0000x reference)
//
#include <hip/hip_runtime.h>
#include <hip/hip_bf16.h>
#include <hip/hip_fp16.h>
#include <math.h>

// ---- types ----
using f32x4  = __attribute__((ext_vector_type(4))) float;
using half8  = __attribute__((ext_vector_type(8))) _Float16;
using uint4v = __attribute__((ext_vector_type(4))) unsigned int;

__device__ __forceinline__ unsigned short f32_to_f16u(float f) {
  return __half_as_ushort(__float2half(f));
}
__device__ __forceinline__ float f16u_to_f32(unsigned short h) {
  return __half2float(__ushort_as_half(h));
}
__device__ __forceinline__ f32x4 mfma16(half8 a, half8 b, f32x4 c) {
  return __builtin_amdgcn_mfma_f32_16x16x32_f16(a, b, c, 0, 0, 0);
}
__device__ __forceinline__ void gload_lds16(void* lds, const void* g) {
  __builtin_amdgcn_global_load_lds(
      (const __attribute__((address_space(1))) unsigned int*)g,
      (__attribute__((address_space(3))) unsigned int*)lds, 16, 0, 0);
}
__device__ __forceinline__ float gelu_exact(float x) {
  return 0.5f * x * (1.0f + erff(x * 0.70710678118654752440f));
}

// ---- problem constants ----
// B=32768, D=768, H1=256, E=128, N=500(pad 512), K_imp=902(pad 960)

// ---------------------------------------------------------------------------
// prep: weight transposes -> f16 [N][K] row-major; centroid pad + norms
// ---------------------------------------------------------------------------
__global__ __launch_bounds__(256) void k_prep(
    const float* __restrict__ enc_w1, const float* __restrict__ enc_w2,
    const float* __restrict__ imp_w1, const float* __restrict__ cent,
    unsigned short* __restrict__ W1T, unsigned short* __restrict__ W2T,
    unsigned short* __restrict__ impW1T, unsigned short* __restrict__ centC,
    float* __restrict__ c_n) {
  int idx = blockIdx.x * 256 + threadIdx.x;
  if (idx < 256 * 768) {               // W1T [256][768]
    int n = idx / 768, k = idx - n * 768;
    W1T[idx] = f32_to_f16u(enc_w1[k * 256 + n]);
  }
  if (idx < 128 * 256) {               // W2T [128][256]
    int n = idx >> 8, k = idx & 255;
    W2T[idx] = f32_to_f16u(enc_w2[k * 128 + n]);
  }
  if (idx < 64 * 960) {                // impW1T [64][960], k>=902 zero
    int n = idx / 960, k = idx - n * 960;
    impW1T[idx] = (k < 902) ? f32_to_f16u(imp_w1[k * 64 + n]) : (unsigned short)0;
  }
  if (idx < 512 * 128) {               // centC [512][128], rows>=500 zero
    int n = idx >> 7, k = idx & 127;
    centC[idx] = (n < 500) ? f32_to_f16u(cent[n * 128 + k]) : (unsigned short)0;
  }
  if (idx < 512) {                     // centroid norms (of f16-rounded values)
    float s = 0.f;
    if (idx < 500) {
      for (int k = 0; k < 128; ++k) {
        float v = f16u_to_f32(f32_to_f16u(cent[idx * 128 + k]));
        s += v * v;
      }
    }
    c_n[idx] = sqrtf(s);
  }
}

// ---------------------------------------------------------------------------
// enc1: h1 = gelu(cue @ W1 + b1)   [32768,768]x[768,256] -> f16 [32768][256]
// tile 128x64, BK=64, 4 waves (2x2), wave = 64x32 (4x2 frags)
// ---------------------------------------------------------------------------
__global__ __launch_bounds__(256) void k_enc1(
    const float* __restrict__ cue, const unsigned short* __restrict__ W1T,
    const float* __restrict__ b1, unsigned short* __restrict__ h1) {
  __shared__ unsigned char smA[16384];   // [128 rows][128 B], XOR-swizzled
  __shared__ unsigned char smB[8192];    // [64 rows][128 B], XOR-swizzled
  const int t = threadIdx.x;
  const int lane = t & 63, w = t >> 6;
  const int wr = w >> 1, wc = w & 1;
  const int g = lane >> 4, c = lane & 15;
  const int row0 = blockIdx.x * 128;
  const int n0 = blockIdx.y * 64;

  f32x4 acc[4][2];
#pragma unroll
  for (int i = 0; i < 4; ++i)
#pragma unroll
    for (int j = 0; j < 2; ++j) acc[i][j] = f32x4{0.f, 0.f, 0.f, 0.f};

  const int srow = t >> 1, shalf = t & 1;
  const int aswz = (srow & 7) << 4;
  const int abyte = srow * 128 + shalf * 64;
  const float* asrc = cue + (size_t)(row0 + srow) * 768 + shalf * 32;

  for (int it = 0; it < 12; ++it) {
    __syncthreads();
    {  // stage A: f32 -> f16, swizzled ds_write
      const float* s = asrc + it * 64;
      unsigned int pk[16];
#pragma unroll
      for (int j = 0; j < 8; ++j) {
        f32x4 f = *(const f32x4*)(s + j * 4);
        pk[j * 2 + 0] = (unsigned int)f32_to_f16u(f[0]) | ((unsigned int)f32_to_f16u(f[1]) << 16);
        pk[j * 2 + 1] = (unsigned int)f32_to_f16u(f[2]) | ((unsigned int)f32_to_f16u(f[3]) << 16);
      }
#pragma unroll
      for (int j = 0; j < 4; ++j) {
        uint4v u = {pk[j * 4 + 0], pk[j * 4 + 1], pk[j * 4 + 2], pk[j * 4 + 3]};
        *(uint4v*)(smA + ((abyte + j * 16) ^ aswz)) = u;
      }
    }
    {  // stage B: global_load_lds with source-side swizzle
#pragma unroll
      for (int i = 0; i < 2; ++i) {
        int L = i * 4096 + t * 16;
        int nl = L >> 7, x = L & 127;
        const unsigned char* gs = (const unsigned char*)W1T +
            ((size_t)(n0 + nl) * 768 + it * 64) * 2 + (x ^ ((nl & 7) << 4));
        gload_lds16(smB + i * 4096 + w * 1024, gs);
      }
    }
    __syncthreads();
#pragma unroll
    for (int ks = 0; ks < 2; ++ks) {
      half8 af[4], bf[2];
#pragma unroll
      for (int mf = 0; mf < 4; ++mf) {
        int m = wr * 64 + mf * 16 + c;
        af[mf] = *(const half8*)(smA + m * 128 + (((ks * 64) + g * 16) ^ ((m & 7) << 4)));
      }
#pragma unroll
      for (int nf = 0; nf < 2; ++nf) {
        int n = wc * 32 + nf * 16 + c;
        bf[nf] = *(const half8*)(smB + n * 128 + (((ks * 64) + g * 16) ^ ((n & 7) << 4)));
      }
#pragma unroll
      for (int mf = 0; mf < 4; ++mf)
#pragma unroll
        for (int nf = 0; nf < 2; ++nf)
          acc[mf][nf] = mfma16(af[mf], bf[nf], acc[mf][nf]);
    }
  }
  // epilogue: + bias, exact gelu, store f16
  float bias[2];
#pragma unroll
  for (int nf = 0; nf < 2; ++nf) bias[nf] = b1[n0 + wc * 32 + nf * 16 + c];
#pragma unroll
  for (int mf = 0; mf < 4; ++mf)
#pragma unroll
    for (int nf = 0; nf < 2; ++nf)
#pragma unroll
      for (int r = 0; r < 4; ++r) {
        float x = acc[mf][nf][r] + bias[nf];
        float gl = gelu_exact(x);
        int m = row0 + wr * 64 + mf * 16 + g * 4 + r;
        int n = n0 + wc * 32 + nf * 16 + c;
        h1[(size_t)m * 256 + n] = f32_to_f16u(gl);
      }
}

// ---------------------------------------------------------------------------
// enc2: enc = h1 @ W2 + b2   [32768,256]x[256,128] -> f16 [32768][128]
// ---------------------------------------------------------------------------
__global__ __launch_bounds__(256) void k_enc2(
    const unsigned short* __restrict__ h1, const unsigned short* __restrict__ W2T,
    const float* __restrict__ b2, unsigned short* __restrict__ enc) {
  __shared__ unsigned char smA[16384];
  __shared__ unsigned char smB[8192];
  const int t = threadIdx.x;
  const int lane = t & 63, w = t >> 6;
  const int wr = w >> 1, wc = w & 1;
  const int g = lane >> 4, c = lane & 15;
  const int row0 = blockIdx.x * 128;
  const int n0 = blockIdx.y * 64;

  f32x4 acc[4][2];
#pragma unroll
  for (int i = 0; i < 4; ++i)
#pragma unroll
    for (int j = 0; j < 2; ++j) acc[i][j] = f32x4{0.f, 0.f, 0.f, 0.f};

  for (int it = 0; it < 4; ++it) {
    __syncthreads();
#pragma unroll
    for (int i = 0; i < 4; ++i) {  // stage A from h1 (f16 already)
      int L = i * 4096 + t * 16;
      int rl = L >> 7, x = L & 127;
      const unsigned char* gs = (const unsigned char*)h1 +
          (size_t)(row0 + rl) * 512 + it * 128 + (x ^ ((rl & 7) << 4));
      gload_lds16(smA + i * 4096 + w * 1024, gs);
    }
#pragma unroll
    for (int i = 0; i < 2; ++i) {  // stage B from W2T
      int L = i * 4096 + t * 16;
      int nl = L >> 7, x = L & 127;
      const unsigned char* gs = (const unsigned char*)W2T +
          (size_t)(n0 + nl) * 512 + it * 128 + (x ^ ((nl & 7) << 4));
      gload_lds16(smB + i * 4096 + w * 1024, gs);
    }
    __syncthreads();
#pragma unroll
    for (int ks = 0; ks < 2; ++ks) {
      half8 af[4], bf[2];
#pragma unroll
      for (int mf = 0; mf < 4; ++mf) {
        int m = wr * 64 + mf * 16 + c;
        af[mf] = *(const half8*)(smA + m * 128 + (((ks * 64) + g * 16) ^ ((m & 7) << 4)));
      }
#pragma unroll
      for (int nf = 0; nf < 2; ++nf) {
        int n = wc * 32 + nf * 16 + c;
        bf[nf] = *(const half8*)(smB + n * 128 + (((ks * 64) + g * 16) ^ ((n & 7) << 4)));
      }
#pragma unroll
      for (int mf = 0; mf < 4; ++mf)
#pragma unroll
        for (int nf = 0; nf < 2; ++nf)
          acc[mf][nf] = mfma16(af[mf], bf[nf], acc[mf][nf]);
    }
  }
  float bias[2];
#pragma unroll
  for (int nf = 0; nf < 2; ++nf) bias[nf] = b2[n0 + wc * 32 + nf * 16 + c];
#pragma unroll
  for (int mf = 0; mf < 4; ++mf)
#pragma unroll
    for (int nf = 0; nf < 2; ++nf)
#pragma unroll
      for (int r = 0; r < 4; ++r) {
        float x = acc[mf][nf][r] + bias[nf];
        int m = row0 + wr * 64 + mf * 16 + g * 4 + r;
        int n = n0 + wc * 32 + nf * 16 + c;
        enc[(size_t)m * 128 + n] = f32_to_f16u(x);
      }
}

// ---------------------------------------------------------------------------
// sims + top5: per block 64 rows; each wave owns 16 full rows x 512 cols.
// cosine = num / max(|e||c|, 1e-8); top-5 via monotone-u32 keys + shfl.
// ---------------------------------------------------------------------------
__global__ __launch_bounds__(256) void k_sims(
    const unsigned short* __restrict__ enc, const unsigned short* __restrict__ centC,
    const float* __restrict__ c_n, float* __restrict__ out) {
  __shared__ unsigned char smC[32768];  // centroid chunk [128][256 B], swizzled
  __shared__ float s_en[64];
  const int t = threadIdx.x, lane = t & 63, w = t >> 6;
  const int g = lane >> 4, c = lane & 15;
  const int row0 = blockIdx.x * 64;

  {  // row norms of enc (f16-rounded values -> consistent with num)
    int r = t >> 2, q = t & 3;
    const unsigned char* base = (const unsigned char*)enc + (size_t)(row0 + r) * 256 + q * 64;
    float s = 0.f;
#pragma unroll
    for (int j = 0; j < 4; ++j) {
      uint4v u = *(const uint4v*)(base + j * 16);
#pragma unroll
      for (int e = 0; e < 4; ++e) {
        float lo = f16u_to_f32((unsigned short)(u[e] & 0xFFFFu));
        float hi = f16u_to_f32((unsigned short)(u[e] >> 16));
        s += lo * lo + hi * hi;
      }
    }
    s += __shfl_xor(s, 1);
    s += __shfl_xor(s, 2);
    if (q == 0) s_en[r] = sqrtf(s);
  }

  // preload the wave's A fragments (16 rows, K=128) straight from global
  half8 af[4];
  {
    const unsigned char* abase =
        (const unsigned char*)enc + (size_t)(row0 + w * 16 + c) * 256 + g * 16;
#pragma unroll
    for (int kk = 0; kk < 4; ++kk) af[kk] = *(const half8*)(abase + kk * 64);
  }

  f32x4 acc[32];
#pragma unroll
  for (int i = 0; i < 32; ++i) acc[i] = f32x4{0.f, 0.f, 0.f, 0.f};

  for (int ch = 0; ch < 4; ++ch) {
    __syncthreads();
#pragma unroll
    for (int i = 0; i < 8; ++i) {
      int L = i * 4096 + t * 16;
      int nl = L >> 8, x = L & 255;
      const unsigned char* gs = (const unsigned char*)centC +
          (size_t)(ch * 128 + nl) * 256 + (x ^ ((nl & 7) << 4));
      gload_lds16(smC + i * 4096 + w * 1024, gs);
    }
    __syncthreads();
#pragma unroll
    for (int nfc = 0; nfc < 8; ++nfc) {
      int nl = nfc * 16 + c;
      const unsigned char* bbase = smC + nl * 256;
      int swz = (nl & 7) << 4;
#pragma unroll
      for (int kk = 0; kk < 4; ++kk) {
        half8 bf = *(const half8*)(bbase + ((kk * 64 + g * 16) ^ swz));
        acc[ch * 8 + nfc] = mfma16(af[kk], bf, acc[ch * 8 + nfc]);
      }
    }
  }
  __syncthreads();

  float en[4];
#pragma unroll
  for (int r = 0; r < 4; ++r) en[r] = s_en[w * 16 + g * 4 + r];
#pragma unroll
  for (int nf = 0; nf < 32; ++nf) {
    float cnv = c_n[nf * 16 + c];
#pragma unroll
    for (int r = 0; r < 4; ++r) {
      float denom = fmaxf(en[r] * cnv, 1e-8f);
      acc[nf][r] = acc[nf][r] * __builtin_amdgcn_rcpf(denom);
    }
  }

  // top-5 per row: key = mono(value) high bits | nf<<4 | lane
#pragma unroll
  for (int r = 0; r < 4; ++r) {
    unsigned int keys[32];
#pragma unroll
    for (int nf = 0; nf < 32; ++nf) {
      int col = nf * 16 + c;
      unsigned int u = __float_as_uint(acc[nf][r]);
      u = (u & 0x80000000u) ? ~u : (u | 0x80000000u);
      keys[nf] = (col < 500) ? ((u & 0xFFFFFE00u) | ((unsigned)nf << 4) | (unsigned)c) : 0u;
    }
    int rowA = row0 + w * 16 + g * 4 + r;
#pragma unroll
    for (int it5 = 0; it5 < 5; ++it5) {
      unsigned int best = 0u;
#pragma unroll
      for (int nf = 0; nf < 32; ++nf) best = (keys[nf] > best) ? keys[nf] : best;
#pragma unroll
      for (int s = 1; s < 16; s <<= 1) {
        unsigned int o = __shfl_xor(best, s);
        best = (o > best) ? o : best;
      }
      if (c == 0) {
        unsigned int m = best & 0xFFFFFE00u;
        unsigned int uu = (m & 0x80000000u) ? (m ^ 0x80000000u) : ~m;
        out[(size_t)rowA * 6 + it5] = __uint_as_float(uu);
      }
#pragma unroll
      for (int nf = 0; nf < 32; ++nf) keys[nf] = (keys[nf] == best) ? 0u : keys[nf];
    }
  }
}

// ---------------------------------------------------------------------------
// importance: gelu(combined @ iW1 + b1) @ iW2 + b2 -> sigmoid * mean(emo)
// combined K layout: cue[0,768) | internal[768,896) | rw,ts,emo[896,902) | 0
// tile 128x64, 4 waves each 32 rows x 64 cols (2x4 frags)
// ---------------------------------------------------------------------------
__global__ __launch_bounds__(256) void k_imp(
    const float* __restrict__ cue, const float* __restrict__ internal,
    const float* __restrict__ reward, const float* __restrict__ tsp,
    const float* __restrict__ emo, const unsigned short* __restrict__ impW1T,
    const float* __restrict__ ib1, const float* __restrict__ iw2,
    const float* __restrict__ ib2, float* __restrict__ out) {
  __shared__ unsigned char smA[16384];
  __shared__ unsigned char smB[8192];
  const int t = threadIdx.x, lane = t & 63, w = t >> 6;
  const int g = lane >> 4, c = lane & 15;
  const int row0 = blockIdx.x * 128;

  f32x4 acc[2][4];
#pragma unroll
  for (int i = 0; i < 2; ++i)
#pragma unroll
    for (int j = 0; j < 4; ++j) acc[i][j] = f32x4{0.f, 0.f, 0.f, 0.f};

  const int srow = t >> 1, shalf = t & 1;
  const int aswz = (srow & 7) << 4;
  const int abyte = srow * 128 + shalf * 64;

  for (int it = 0; it < 15; ++it) {
    __syncthreads();
    {  // stage A
      float v[32];
      if (it < 12) {
        const float* s = cue + (size_t)(row0 + srow) * 768 + it * 64 + shalf * 32;
#pragma unroll
        for (int j = 0; j < 8; ++j) {
          f32x4 f = *(const f32x4*)(s + j * 4);
          v[j * 4 + 0] = f[0]; v[j * 4 + 1] = f[1]; v[j * 4 + 2] = f[2]; v[j * 4 + 3] = f[3];
        }
      } else if (it < 14) {
        const float* s = internal + (size_t)(row0 + srow) * 128 + (it - 12) * 64 + shalf * 32;
#pragma unroll
        for (int j = 0; j < 8; ++j) {
          f32x4 f = *(const f32x4*)(s + j * 4);
          v[j * 4 + 0] = f[0]; v[j * 4 + 1] = f[1]; v[j * 4 + 2] = f[2]; v[j * 4 + 3] = f[3];
        }
      } else {
#pragma unroll
        for (int j = 0; j < 32; ++j) v[j] = 0.f;
        if (shalf == 0) {
          int rr = row0 + srow;
          v[0] = reward[rr]; v[1] = tsp[rr];
          v[2] = emo[rr * 4 + 0]; v[3] = emo[rr * 4 + 1];
          v[4] = emo[rr * 4 + 2]; v[5] = emo[rr * 4 + 3];
        }
      }
      unsigned int pk[16];
#pragma unroll
      for (int j = 0; j < 16; ++j)
        pk[j] = (unsigned int)f32_to_f16u(v[2 * j]) | ((unsigned int)f32_to_f16u(v[2 * j + 1]) << 16);
#pragma unroll
      for (int j = 0; j < 4; ++j) {
        uint4v u = {pk[j * 4 + 0], pk[j * 4 + 1], pk[j * 4 + 2], pk[j * 4 + 3]};
        *(uint4v*)(smA + ((abyte + j * 16) ^ aswz)) = u;
      }
    }
#pragma unroll
    for (int i = 0; i < 2; ++i) {  // stage B from impW1T [64][960]
      int L = i * 4096 + t * 16;
      int nl = L >> 7, x = L & 127;
      const unsigned char* gs = (const unsigned char*)impW1T +
          (size_t)nl * 1920 + it * 128 + (x ^ ((nl & 7) << 4));
      gload_lds16(smB + i * 4096 + w * 1024, gs);
    }
    __syncthreads();
#pragma unroll
    for (int ks = 0; ks < 2; ++ks) {
      half8 afr[2], bfr[4];
#pragma unroll
      for (int mf = 0; mf < 2; ++mf) {
        int m = w * 32 + mf * 16 + c;
        afr[mf] = *(const half8*)(smA + m * 128 + (((ks * 64) + g * 16) ^ ((m & 7) << 4)));
      }
#pragma unroll
      for (int nf = 0; nf < 4; ++nf) {
        int n = nf * 16 + c;
        bfr[nf] = *(const half8*)(smB + n * 128 + (((ks * 64) + g * 16) ^ ((n & 7) << 4)));
      }
#pragma unroll
      for (int mf = 0; mf < 2; ++mf)
#pragma unroll
        for (int nf = 0; nf < 4; ++nf)
          acc[mf][nf] = mfma16(afr[mf], bfr[nf], acc[mf][nf]);
    }
  }
  // epilogue: gelu, dot with w2 across 64 hidden, sigmoid * mean(emo)
  float b1v[4], w2v[4];
#pragma unroll
  for (int nf = 0; nf < 4; ++nf) {
    b1v[nf] = ib1[nf * 16 + c];
    w2v[nf] = iw2[nf * 16 + c];
  }
  float bias2 = ib2[0];
#pragma unroll
  for (int mf = 0; mf < 2; ++mf) {
#pragma unroll
    for (int r = 0; r < 4; ++r) {
      float p = 0.f;
#pragma unroll
      for (int nf = 0; nf < 4; ++nf)
        p += gelu_exact(acc[mf][nf][r] + b1v[nf]) * w2v[nf];
      p += __shfl_xor(p, 1);
      p += __shfl_xor(p, 2);
      p += __shfl_xor(p, 4);
      p += __shfl_xor(p, 8);
      if (c == 0) {
        int rowA = row0 + w * 32 + mf * 16 + g * 4 + r;
        float z = p + bias2;
        float sig = 1.0f / (1.0f + expf(-z));
        float m4 = 0.25f * (emo[rowA * 4 + 0] + emo[rowA * 4 + 1] +
                            emo[rowA * 4 + 2] + emo[rowA * 4 + 3]);
        out[(size_t)rowA * 6 + 5] = sig * m4;
      }
    }
  }
}

// ---------------------------------------------------------------------------
extern "C" void kernel_launch(void* const* d_in, const int* in_sizes, int n_in,
                              void* d_out, int out_size, void* d_ws, size_t ws_size,
                              hipStream_t stream) {
  (void)in_sizes; (void)n_in; (void)out_size; (void)ws_size;
  const float* cue      = (const float*)d_in[0];
  const float* internal = (const float*)d_in[1];
  const float* reward   = (const float*)d_in[2];
  const float* tsp      = (const float*)d_in[3];
  const float* emo      = (const float*)d_in[4];
  const float* cent     = (const float*)d_in[5];
  const float* enc_w1   = (const float*)d_in[6];
  const float* enc_b1   = (const float*)d_in[7];
  const float* enc_w2   = (const float*)d_in[8];
  const float* enc_b2   = (const float*)d_in[9];
  const float* imp_w1   = (const float*)d_in[10];
  const float* imp_b1   = (const float*)d_in[11];
  const float* imp_w2   = (const float*)d_in[12];
  const float* imp_b2   = (const float*)d_in[13];
  float* out = (float*)d_out;

  unsigned char* ws = (unsigned char*)d_ws;
  unsigned short* h1     = (unsigned short*)(ws + 0);         // 32768*256*2 = 16777216
  unsigned short* enc    = (unsigned short*)(ws + 16777216);  // 32768*128*2 =  8388608
  unsigned short* W1T    = (unsigned short*)(ws + 25165824);  // 256*768*2   =   393216
  unsigned short* W2T    = (unsigned short*)(ws + 25559040);  // 128*256*2   =    65536
  unsigned short* impW1T = (unsigned short*)(ws + 25624576);  // 64*960*2    =   122880
  unsigned short* centC  = (unsigned short*)(ws + 25747456);  // 512*128*2   =   131072
  float*          c_n    = (float*)(ws + 25878528);           // 512*4       =     2048

  k_prep<<<768, 256, 0, stream>>>(enc_w1, enc_w2, imp_w1, cent, W1T, W2T, impW1T, centC, c_n);
  k_enc1<<<dim3(256, 4), 256, 0, stream>>>(cue, W1T, enc_b1, h1);
  k_enc2<<<dim3(256, 2), 256, 0, stream>>>(h1, W2T, enc_b2, enc);
  k_sims<<<512, 256, 0, stream>>>(enc, centC, c_n, out);
  k_imp<<<256, 256, 0, stream>>>(cue, internal, reward, tsp, emo, impW1T, imp_b1, imp_w2, imp_b2, out);
}

// Round 2
// 139.551 us; speedup vs baseline: 1.1136x; 1.1136x over previous
//
#include <hip/hip_runtime.h>
#include <hip/hip_bf16.h>
#include <hip/hip_fp16.h>
#include <math.h>

// ---- types ----
using f32x4  = __attribute__((ext_vector_type(4))) float;
using half8  = __attribute__((ext_vector_type(8))) _Float16;
using uint4v = __attribute__((ext_vector_type(4))) unsigned int;

__device__ __forceinline__ unsigned short f32_to_f16u(float f) {
  return __half_as_ushort(__float2half(f));
}
__device__ __forceinline__ float f16u_to_f32(unsigned short h) {
  return __half2float(__ushort_as_half(h));
}
__device__ __forceinline__ f32x4 mfma16(half8 a, half8 b, f32x4 c) {
  return __builtin_amdgcn_mfma_f32_16x16x32_f16(a, b, c, 0, 0, 0);
}
__device__ __forceinline__ void gload_lds16(void* lds, const void* g) {
  __builtin_amdgcn_global_load_lds(
      (const __attribute__((address_space(1))) unsigned int*)g,
      (__attribute__((address_space(3))) unsigned int*)lds, 16, 0, 0);
}
__device__ __forceinline__ float gelu_exact(float x) {
  return 0.5f * x * (1.0f + erff(x * 0.70710678118654752440f));
}

// ---- problem constants ----
// B=32768, D=768, H1=256, E=128, N=500(pad 512), K_imp=902(pad 960)

// ---------------------------------------------------------------------------
// prep: weight transposes -> f16 [N][K] row-major; centroid pad + norms
// ---------------------------------------------------------------------------
__global__ __launch_bounds__(256) void k_prep(
    const float* __restrict__ enc_w1, const float* __restrict__ enc_w2,
    const float* __restrict__ imp_w1, const float* __restrict__ cent,
    unsigned short* __restrict__ W1T, unsigned short* __restrict__ W2T,
    unsigned short* __restrict__ impW1T, unsigned short* __restrict__ centC,
    float* __restrict__ c_n) {
  int idx = blockIdx.x * 256 + threadIdx.x;
  if (idx < 256 * 768) {               // W1T [256][768]
    int n = idx / 768, k = idx - n * 768;
    W1T[idx] = f32_to_f16u(enc_w1[k * 256 + n]);
  }
  if (idx < 128 * 256) {               // W2T [128][256]
    int n = idx >> 8, k = idx & 255;
    W2T[idx] = f32_to_f16u(enc_w2[k * 128 + n]);
  }
  if (idx < 64 * 960) {                // impW1T [64][960], k>=902 zero
    int n = idx / 960, k = idx - n * 960;
    impW1T[idx] = (k < 902) ? f32_to_f16u(imp_w1[k * 64 + n]) : (unsigned short)0;
  }
  if (idx < 512 * 128) {               // centC [512][128], rows>=500 zero
    int n = idx >> 7, k = idx & 127;
    centC[idx] = (n < 500) ? f32_to_f16u(cent[n * 128 + k]) : (unsigned short)0;
  }
  if (idx < 512) {                     // centroid norms (of f16-rounded values)
    float s = 0.f;
    if (idx < 500) {
      for (int k = 0; k < 128; ++k) {
        float v = f16u_to_f32(f32_to_f16u(cent[idx * 128 + k]));
        s += v * v;
      }
    }
    c_n[idx] = sqrtf(s);
  }
}

// ---------------------------------------------------------------------------
// enc1: h1 = gelu(cue @ W1 + b1)   [32768,768]x[768,256] -> f16 [32768][256]
// tile 128x64, BK=64, 4 waves (2x2), wave = 64x32 (4x2 frags)
// ---------------------------------------------------------------------------
__global__ __launch_bounds__(256) void k_enc1(
    const float* __restrict__ cue, const unsigned short* __restrict__ W1T,
    const float* __restrict__ b1, unsigned short* __restrict__ h1) {
  __shared__ unsigned char smA[16384];   // [128 rows][128 B], XOR-swizzled
  __shared__ unsigned char smB[8192];    // [64 rows][128 B], XOR-swizzled
  const int t = threadIdx.x;
  const int lane = t & 63, w = t >> 6;
  const int wr = w >> 1, wc = w & 1;
  const int g = lane >> 4, c = lane & 15;
  const int row0 = blockIdx.x * 128;
  const int n0 = blockIdx.y * 64;

  f32x4 acc[4][2];
#pragma unroll
  for (int i = 0; i < 4; ++i)
#pragma unroll
    for (int j = 0; j < 2; ++j) acc[i][j] = f32x4{0.f, 0.f, 0.f, 0.f};

  const int srow = t >> 1, shalf = t & 1;
  const int aswz = (srow & 7) << 4;
  const int abyte = srow * 128 + shalf * 64;
  const float* asrc = cue + (size_t)(row0 + srow) * 768 + shalf * 32;

  for (int it = 0; it < 12; ++it) {
    __syncthreads();
    {  // stage A: f32 -> f16, swizzled ds_write
      const float* s = asrc + it * 64;
      unsigned int pk[16];
#pragma unroll
      for (int j = 0; j < 8; ++j) {
        f32x4 f = *(const f32x4*)(s + j * 4);
        pk[j * 2 + 0] = (unsigned int)f32_to_f16u(f[0]) | ((unsigned int)f32_to_f16u(f[1]) << 16);
        pk[j * 2 + 1] = (unsigned int)f32_to_f16u(f[2]) | ((unsigned int)f32_to_f16u(f[3]) << 16);
      }
#pragma unroll
      for (int j = 0; j < 4; ++j) {
        uint4v u = {pk[j * 4 + 0], pk[j * 4 + 1], pk[j * 4 + 2], pk[j * 4 + 3]};
        *(uint4v*)(smA + ((abyte + j * 16) ^ aswz)) = u;
      }
    }
    {  // stage B: global_load_lds with source-side swizzle
#pragma unroll
      for (int i = 0; i < 2; ++i) {
        int L = i * 4096 + t * 16;
        int nl = L >> 7, x = L & 127;
        const unsigned char* gs = (const unsigned char*)W1T +
            ((size_t)(n0 + nl) * 768 + it * 64) * 2 + (x ^ ((nl & 7) << 4));
        gload_lds16(smB + i * 4096 + w * 1024, gs);
      }
    }
    __syncthreads();
#pragma unroll
    for (int ks = 0; ks < 2; ++ks) {
      half8 af[4], bf[2];
#pragma unroll
      for (int mf = 0; mf < 4; ++mf) {
        int m = wr * 64 + mf * 16 + c;
        af[mf] = *(const half8*)(smA + m * 128 + (((ks * 64) + g * 16) ^ ((m & 7) << 4)));
      }
#pragma unroll
      for (int nf = 0; nf < 2; ++nf) {
        int n = wc * 32 + nf * 16 + c;
        bf[nf] = *(const half8*)(smB + n * 128 + (((ks * 64) + g * 16) ^ ((n & 7) << 4)));
      }
#pragma unroll
      for (int mf = 0; mf < 4; ++mf)
#pragma unroll
        for (int nf = 0; nf < 2; ++nf)
          acc[mf][nf] = mfma16(af[mf], bf[nf], acc[mf][nf]);
    }
  }
  // epilogue: + bias, exact gelu, store f16
  float bias[2];
#pragma unroll
  for (int nf = 0; nf < 2; ++nf) bias[nf] = b1[n0 + wc * 32 + nf * 16 + c];
#pragma unroll
  for (int mf = 0; mf < 4; ++mf)
#pragma unroll
    for (int nf = 0; nf < 2; ++nf)
#pragma unroll
      for (int r = 0; r < 4; ++r) {
        float x = acc[mf][nf][r] + bias[nf];
        float gl = gelu_exact(x);
        int m = row0 + wr * 64 + mf * 16 + g * 4 + r;
        int n = n0 + wc * 32 + nf * 16 + c;
        h1[(size_t)m * 256 + n] = f32_to_f16u(gl);
      }
}

// ---------------------------------------------------------------------------
// enc2: enc = h1 @ W2 + b2   [32768,256]x[256,128] -> f16 [32768][128]
// ---------------------------------------------------------------------------
__global__ __launch_bounds__(256) void k_enc2(
    const unsigned short* __restrict__ h1, const unsigned short* __restrict__ W2T,
    const float* __restrict__ b2, unsigned short* __restrict__ enc) {
  __shared__ unsigned char smA[16384];
  __shared__ unsigned char smB[8192];
  const int t = threadIdx.x;
  const int lane = t & 63, w = t >> 6;
  const int wr = w >> 1, wc = w & 1;
  const int g = lane >> 4, c = lane & 15;
  const int row0 = blockIdx.x * 128;
  const int n0 = blockIdx.y * 64;

  f32x4 acc[4][2];
#pragma unroll
  for (int i = 0; i < 4; ++i)
#pragma unroll
    for (int j = 0; j < 2; ++j) acc[i][j] = f32x4{0.f, 0.f, 0.f, 0.f};

  for (int it = 0; it < 4; ++it) {
    __syncthreads();
#pragma unroll
    for (int i = 0; i < 4; ++i) {  // stage A from h1 (f16 already)
      int L = i * 4096 + t * 16;
      int rl = L >> 7, x = L & 127;
      const unsigned char* gs = (const unsigned char*)h1 +
          (size_t)(row0 + rl) * 512 + it * 128 + (x ^ ((rl & 7) << 4));
      gload_lds16(smA + i * 4096 + w * 1024, gs);
    }
#pragma unroll
    for (int i = 0; i < 2; ++i) {  // stage B from W2T
      int L = i * 4096 + t * 16;
      int nl = L >> 7, x = L & 127;
      const unsigned char* gs = (const unsigned char*)W2T +
          (size_t)(n0 + nl) * 512 + it * 128 + (x ^ ((nl & 7) << 4));
      gload_lds16(smB + i * 4096 + w * 1024, gs);
    }
    __syncthreads();
#pragma unroll
    for (int ks = 0; ks < 2; ++ks) {
      half8 af[4], bf[2];
#pragma unroll
      for (int mf = 0; mf < 4; ++mf) {
        int m = wr * 64 + mf * 16 + c;
        af[mf] = *(const half8*)(smA + m * 128 + (((ks * 64) + g * 16) ^ ((m & 7) << 4)));
      }
#pragma unroll
      for (int nf = 0; nf < 2; ++nf) {
        int n = wc * 32 + nf * 16 + c;
        bf[nf] = *(const half8*)(smB + n * 128 + (((ks * 64) + g * 16) ^ ((n & 7) << 4)));
      }
#pragma unroll
      for (int mf = 0; mf < 4; ++mf)
#pragma unroll
        for (int nf = 0; nf < 2; ++nf)
          acc[mf][nf] = mfma16(af[mf], bf[nf], acc[mf][nf]);
    }
  }
  float bias[2];
#pragma unroll
  for (int nf = 0; nf < 2; ++nf) bias[nf] = b2[n0 + wc * 32 + nf * 16 + c];
#pragma unroll
  for (int mf = 0; mf < 4; ++mf)
#pragma unroll
    for (int nf = 0; nf < 2; ++nf)
#pragma unroll
      for (int r = 0; r < 4; ++r) {
        float x = acc[mf][nf][r] + bias[nf];
        int m = row0 + wr * 64 + mf * 16 + g * 4 + r;
        int n = n0 + wc * 32 + nf * 16 + c;
        enc[(size_t)m * 128 + n] = f32_to_f16u(x);
      }
}

// ---------------------------------------------------------------------------
// sims + top5 (streaming): per block 64 rows; each wave 16 rows x 512 cols,
// processed in 4 chunks of 128 cols. Per chunk only acc[8] live; cosine ->
// monotone-u32 key -> branchless insert into running sorted top-5 (per row).
// Final: 5 x {16-lane shfl-max of heads, pop at owner}.
// ---------------------------------------------------------------------------
__global__ __launch_bounds__(256) void k_sims(
    const unsigned short* __restrict__ enc, const unsigned short* __restrict__ centC,
    const float* __restrict__ c_n, float* __restrict__ out) {
  __shared__ unsigned char smC[32768];  // centroid chunk [128][256 B], swizzled
  __shared__ float s_en[64];
  const int t = threadIdx.x, lane = t & 63, w = t >> 6;
  const int g = lane >> 4, c = lane & 15;
  const int row0 = blockIdx.x * 64;

  {  // row norms of enc (f16-rounded values -> consistent with num)
    int r = t >> 2, q = t & 3;
    const unsigned char* base = (const unsigned char*)enc + (size_t)(row0 + r) * 256 + q * 64;
    float s = 0.f;
#pragma unroll
    for (int j = 0; j < 4; ++j) {
      uint4v u = *(const uint4v*)(base + j * 16);
#pragma unroll
      for (int e = 0; e < 4; ++e) {
        float lo = f16u_to_f32((unsigned short)(u[e] & 0xFFFFu));
        float hi = f16u_to_f32((unsigned short)(u[e] >> 16));
        s += lo * lo + hi * hi;
      }
    }
    s += __shfl_xor(s, 1);
    s += __shfl_xor(s, 2);
    if (q == 0) s_en[r] = sqrtf(s);
  }
  __syncthreads();

  float en[4];
#pragma unroll
  for (int r = 0; r < 4; ++r) en[r] = s_en[w * 16 + g * 4 + r];

  // preload the wave's A fragments (16 rows, K=128) straight from global
  half8 af[4];
  {
    const unsigned char* abase =
        (const unsigned char*)enc + (size_t)(row0 + w * 16 + c) * 256 + g * 16;
#pragma unroll
    for (int kk = 0; kk < 4; ++kk) af[kk] = *(const half8*)(abase + kk * 64);
  }

  unsigned int top5[4][5];
#pragma unroll
  for (int r = 0; r < 4; ++r)
#pragma unroll
    for (int s5 = 0; s5 < 5; ++s5) top5[r][s5] = 0u;

#pragma unroll
  for (int ch = 0; ch < 4; ++ch) {
    __syncthreads();
#pragma unroll
    for (int i = 0; i < 8; ++i) {
      int L = i * 4096 + t * 16;
      int nl = L >> 8, x = L & 255;
      const unsigned char* gs = (const unsigned char*)centC +
          (size_t)(ch * 128 + nl) * 256 + (x ^ ((nl & 7) << 4));
      gload_lds16(smC + i * 4096 + w * 1024, gs);
    }
    __syncthreads();

    f32x4 acc[8];
#pragma unroll
    for (int i = 0; i < 8; ++i) acc[i] = f32x4{0.f, 0.f, 0.f, 0.f};
#pragma unroll
    for (int nfc = 0; nfc < 8; ++nfc) {
      int nl = nfc * 16 + c;
      const unsigned char* bbase = smC + nl * 256;
      int swz = (nl & 7) << 4;
#pragma unroll
      for (int kk = 0; kk < 4; ++kk) {
        half8 bf = *(const half8*)(bbase + ((kk * 64 + g * 16) ^ swz));
        acc[nfc] = mfma16(af[kk], bf, acc[nfc]);
      }
    }

    // scale to cosine, make keys, insert into running top-5
#pragma unroll
    for (int nfc = 0; nfc < 8; ++nfc) {
      int col = ch * 128 + nfc * 16 + c;
      float cnv = c_n[col];
#pragma unroll
      for (int r = 0; r < 4; ++r) {
        float denom = fmaxf(en[r] * cnv, 1e-8f);
        float v = acc[nfc][r] * __builtin_amdgcn_rcpf(denom);
        unsigned int u = __float_as_uint(v);
        u = (u & 0x80000000u) ? ~u : (u | 0x80000000u);
        unsigned int k = (col < 500) ? ((u & 0xFFFFFE00u) | (unsigned)col) : 0u;
        unsigned int t0 = top5[r][0], t1 = top5[r][1], t2 = top5[r][2],
                     t3 = top5[r][3], t4 = top5[r][4];
        top5[r][0] = (k > t0) ? k : t0;
        top5[r][1] = (k > t0) ? t0 : ((k > t1) ? k : t1);
        top5[r][2] = (k > t1) ? t1 : ((k > t2) ? k : t2);
        top5[r][3] = (k > t2) ? t2 : ((k > t3) ? k : t3);
        top5[r][4] = (k > t3) ? t3 : ((k > t4) ? k : t4);
      }
    }
  }

  // final: per row, 5 rounds of 16-lane max over list heads
#pragma unroll
  for (int r = 0; r < 4; ++r) {
    int rowA = row0 + w * 16 + g * 4 + r;
    unsigned int h0 = top5[r][0], h1 = top5[r][1], h2 = top5[r][2],
                 h3 = top5[r][3], h4 = top5[r][4];
#pragma unroll
    for (int it5 = 0; it5 < 5; ++it5) {
      unsigned int best = h0;
#pragma unroll
      for (int s = 1; s < 16; s <<= 1) {
        unsigned int o = __shfl_xor(best, s);
        best = (o > best) ? o : best;
      }
      if (c == 0) {
        unsigned int m = best & 0xFFFFFE00u;
        unsigned int uu = (m & 0x80000000u) ? (m ^ 0x80000000u) : ~m;
        out[(size_t)rowA * 6 + it5] = __uint_as_float(uu);
      }
      bool pop = (h0 == best);
      h0 = pop ? h1 : h0;
      h1 = pop ? h2 : h1;
      h2 = pop ? h3 : h2;
      h3 = pop ? h4 : h3;
      h4 = pop ? 0u : h4;
    }
  }
}

// ---------------------------------------------------------------------------
// importance: gelu(combined @ iW1 + b1) @ iW2 + b2 -> sigmoid * mean(emo)
// combined K layout: cue[0,768) | internal[768,896) | rw,ts,emo[896,902) | 0
// tile 128x64, 4 waves each 32 rows x 64 cols (2x4 frags)
// ---------------------------------------------------------------------------
__global__ __launch_bounds__(256) void k_imp(
    const float* __restrict__ cue, const float* __restrict__ internal,
    const float* __restrict__ reward, const float* __restrict__ tsp,
    const float* __restrict__ emo, const unsigned short* __restrict__ impW1T,
    const float* __restrict__ ib1, const float* __restrict__ iw2,
    const float* __restrict__ ib2, float* __restrict__ out) {
  __shared__ unsigned char smA[16384];
  __shared__ unsigned char smB[8192];
  const int t = threadIdx.x, lane = t & 63, w = t >> 6;
  const int g = lane >> 4, c = lane & 15;
  const int row0 = blockIdx.x * 128;

  f32x4 acc[2][4];
#pragma unroll
  for (int i = 0; i < 2; ++i)
#pragma unroll
    for (int j = 0; j < 4; ++j) acc[i][j] = f32x4{0.f, 0.f, 0.f, 0.f};

  const int srow = t >> 1, shalf = t & 1;
  const int aswz = (srow & 7) << 4;
  const int abyte = srow * 128 + shalf * 64;

  for (int it = 0; it < 15; ++it) {
    __syncthreads();
    {  // stage A
      float v[32];
      if (it < 12) {
        const float* s = cue + (size_t)(row0 + srow) * 768 + it * 64 + shalf * 32;
#pragma unroll
        for (int j = 0; j < 8; ++j) {
          f32x4 f = *(const f32x4*)(s + j * 4);
          v[j * 4 + 0] = f[0]; v[j * 4 + 1] = f[1]; v[j * 4 + 2] = f[2]; v[j * 4 + 3] = f[3];
        }
      } else if (it < 14) {
        const float* s = internal + (size_t)(row0 + srow) * 128 + (it - 12) * 64 + shalf * 32;
#pragma unroll
        for (int j = 0; j < 8; ++j) {
          f32x4 f = *(const f32x4*)(s + j * 4);
          v[j * 4 + 0] = f[0]; v[j * 4 + 1] = f[1]; v[j * 4 + 2] = f[2]; v[j * 4 + 3] = f[3];
        }
      } else {
#pragma unroll
        for (int j = 0; j < 32; ++j) v[j] = 0.f;
        if (shalf == 0) {
          int rr = row0 + srow;
          v[0] = reward[rr]; v[1] = tsp[rr];
          v[2] = emo[rr * 4 + 0]; v[3] = emo[rr * 4 + 1];
          v[4] = emo[rr * 4 + 2]; v[5] = emo[rr * 4 + 3];
        }
      }
      unsigned int pk[16];
#pragma unroll
      for (int j = 0; j < 16; ++j)
        pk[j] = (unsigned int)f32_to_f16u(v[2 * j]) | ((unsigned int)f32_to_f16u(v[2 * j + 1]) << 16);
#pragma unroll
      for (int j = 0; j < 4; ++j) {
        uint4v u = {pk[j * 4 + 0], pk[j * 4 + 1], pk[j * 4 + 2], pk[j * 4 + 3]};
        *(uint4v*)(smA + ((abyte + j * 16) ^ aswz)) = u;
      }
    }
#pragma unroll
    for (int i = 0; i < 2; ++i) {  // stage B from impW1T [64][960]
      int L = i * 4096 + t * 16;
      int nl = L >> 7, x = L & 127;
      const unsigned char* gs = (const unsigned char*)impW1T +
          (size_t)nl * 1920 + it * 128 + (x ^ ((nl & 7) << 4));
      gload_lds16(smB + i * 4096 + w * 1024, gs);
    }
    __syncthreads();
#pragma unroll
    for (int ks = 0; ks < 2; ++ks) {
      half8 afr[2], bfr[4];
#pragma unroll
      for (int mf = 0; mf < 2; ++mf) {
        int m = w * 32 + mf * 16 + c;
        afr[mf] = *(const half8*)(smA + m * 128 + (((ks * 64) + g * 16) ^ ((m & 7) << 4)));
      }
#pragma unroll
      for (int nf = 0; nf < 4; ++nf) {
        int n = nf * 16 + c;
        bfr[nf] = *(const half8*)(smB + n * 128 + (((ks * 64) + g * 16) ^ ((n & 7) << 4)));
      }
#pragma unroll
      for (int mf = 0; mf < 2; ++mf)
#pragma unroll
        for (int nf = 0; nf < 4; ++nf)
          acc[mf][nf] = mfma16(afr[mf], bfr[nf], acc[mf][nf]);
    }
  }
  // epilogue: gelu, dot with w2 across 64 hidden, sigmoid * mean(emo)
  float b1v[4], w2v[4];
#pragma unroll
  for (int nf = 0; nf < 4; ++nf) {
    b1v[nf] = ib1[nf * 16 + c];
    w2v[nf] = iw2[nf * 16 + c];
  }
  float bias2 = ib2[0];
#pragma unroll
  for (int mf = 0; mf < 2; ++mf) {
#pragma unroll
    for (int r = 0; r < 4; ++r) {
      float p = 0.f;
#pragma unroll
      for (int nf = 0; nf < 4; ++nf)
        p += gelu_exact(acc[mf][nf][r] + b1v[nf]) * w2v[nf];
      p += __shfl_xor(p, 1);
      p += __shfl_xor(p, 2);
      p += __shfl_xor(p, 4);
      p += __shfl_xor(p, 8);
      if (c == 0) {
        int rowA = row0 + w * 32 + mf * 16 + g * 4 + r;
        float z = p + bias2;
        float sig = 1.0f / (1.0f + expf(-z));
        float m4 = 0.25f * (emo[rowA * 4 + 0] + emo[rowA * 4 + 1] +
                            emo[rowA * 4 + 2] + emo[rowA * 4 + 3]);
        out[(size_t)rowA * 6 + 5] = sig * m4;
      }
    }
  }
}

// ---------------------------------------------------------------------------
extern "C" void kernel_launch(void* const* d_in, const int* in_sizes, int n_in,
                              void* d_out, int out_size, void* d_ws, size_t ws_size,
                              hipStream_t stream) {
  (void)in_sizes; (void)n_in; (void)out_size; (void)ws_size;
  const float* cue      = (const float*)d_in[0];
  const float* internal = (const float*)d_in[1];
  const float* reward   = (const float*)d_in[2];
  const float* tsp      = (const float*)d_in[3];
  const float* emo      = (const float*)d_in[4];
  const float* cent     = (const float*)d_in[5];
  const float* enc_w1   = (const float*)d_in[6];
  const float* enc_b1   = (const float*)d_in[7];
  const float* enc_w2   = (const float*)d_in[8];
  const float* enc_b2   = (const float*)d_in[9];
  const float* imp_w1   = (const float*)d_in[10];
  const float* imp_b1   = (const float*)d_in[11];
  const float* imp_w2   = (const float*)d_in[12];
  const float* imp_b2   = (const float*)d_in[13];
  float* out = (float*)d_out;

  unsigned char* ws = (unsigned char*)d_ws;
  unsigned short* h1     = (unsigned short*)(ws + 0);         // 32768*256*2 = 16777216
  unsigned short* enc    = (unsigned short*)(ws + 16777216);  // 32768*128*2 =  8388608
  unsigned short* W1T    = (unsigned short*)(ws + 25165824);  // 256*768*2   =   393216
  unsigned short* W2T    = (unsigned short*)(ws + 25559040);  // 128*256*2   =    65536
  unsigned short* impW1T = (unsigned short*)(ws + 25624576);  // 64*960*2    =   122880
  unsigned short* centC  = (unsigned short*)(ws + 25747456);  // 512*128*2   =   131072
  float*          c_n    = (float*)(ws + 25878528);           // 512*4       =     2048

  k_prep<<<768, 256, 0, stream>>>(enc_w1, enc_w2, imp_w1, cent, W1T, W2T, impW1T, centC, c_n);
  k_enc1<<<dim3(256, 4), 256, 0, stream>>>(cue, W1T, enc_b1, h1);
  k_enc2<<<dim3(256, 2), 256, 0, stream>>>(h1, W2T, enc_b2, enc);
  k_sims<<<512, 256, 0, stream>>>(enc, centC, c_n, out);
  k_imp<<<256, 256, 0, stream>>>(cue, internal, reward, tsp, emo, impW1T, imp_b1, imp_w2, imp_b2, out);
}

// Round 3
// 80.825 us; speedup vs baseline: 1.9228x; 1.7266x over previous
//
#include <hip/hip_runtime.h>
#include <hip/hip_bf16.h>
#include <hip/hip_fp16.h>
#include <math.h>

// ---- types ----
using f32x4  = __attribute__((ext_vector_type(4))) float;
using half8  = __attribute__((ext_vector_type(8))) _Float16;
using uint4v = __attribute__((ext_vector_type(4))) unsigned int;

#define VMCNT0 asm volatile("s_waitcnt vmcnt(0)" ::: "memory")
#define LGKM0  asm volatile("s_waitcnt lgkmcnt(0)" ::: "memory")
#define SBAR   __builtin_amdgcn_s_barrier()

__device__ __forceinline__ unsigned short f32_to_f16u(float f) {
  return __half_as_ushort(__float2half(f));
}
__device__ __forceinline__ float f16u_to_f32(unsigned short h) {
  return __half2float(__ushort_as_half(h));
}
__device__ __forceinline__ f32x4 mfma16(half8 a, half8 b, f32x4 c) {
  return __builtin_amdgcn_mfma_f32_16x16x32_f16(a, b, c, 0, 0, 0);
}
__device__ __forceinline__ void gload_lds16(void* lds, const void* g) {
  __builtin_amdgcn_global_load_lds(
      (const __attribute__((address_space(1))) unsigned int*)g,
      (__attribute__((address_space(3))) unsigned int*)lds, 16, 0, 0);
}
__device__ __forceinline__ float gelu_exact(float x) {
  return 0.5f * x * (1.0f + erff(x * 0.70710678118654752440f));
}

// ---- problem constants ----
// B=32768, D=768, H1=256, E=128, N=500(pad 512), K_imp=902(pad 960)

// ---------------------------------------------------------------------------
// prep: weight transposes -> f16 [N][K] row-major; centroid pad + norms
// ---------------------------------------------------------------------------
__global__ __launch_bounds__(256) void k_prep(
    const float* __restrict__ enc_w1, const float* __restrict__ enc_w2,
    const float* __restrict__ imp_w1, const float* __restrict__ cent,
    unsigned short* __restrict__ W1T, unsigned short* __restrict__ W2T,
    unsigned short* __restrict__ impW1T, unsigned short* __restrict__ centC,
    float* __restrict__ c_n) {
  int idx = blockIdx.x * 256 + threadIdx.x;
  if (idx < 256 * 768) {               // W1T [256][768]
    int n = idx / 768, k = idx - n * 768;
    W1T[idx] = f32_to_f16u(enc_w1[k * 256 + n]);
  }
  if (idx < 128 * 256) {               // W2T [128][256]
    int n = idx >> 8, k = idx & 255;
    W2T[idx] = f32_to_f16u(enc_w2[k * 128 + n]);
  }
  if (idx < 64 * 960) {                // impW1T [64][960], k>=902 zero
    int n = idx / 960, k = idx - n * 960;
    impW1T[idx] = (k < 902) ? f32_to_f16u(imp_w1[k * 64 + n]) : (unsigned short)0;
  }
  if (idx < 512 * 128) {               // centC [512][128], rows>=500 zero
    int n = idx >> 7, k = idx & 127;
    centC[idx] = (n < 500) ? f32_to_f16u(cent[n * 128 + k]) : (unsigned short)0;
  }
  if (idx < 512) {                     // centroid norms (of f16-rounded values)
    float s = 0.f;
    if (idx < 500) {
      for (int k = 0; k < 128; ++k) {
        float v = f16u_to_f32(f32_to_f16u(cent[idx * 128 + k]));
        s += v * v;
      }
    }
    c_n[idx] = sqrtf(s);
  }
}

// ---------------------------------------------------------------------------
// fused enc1 + importance:
//   h1  = gelu(cue @ W1 + b1)                      [32768][256] f16 out
//   imp = sigmoid(gelu(comb @ iW1 + ib1) @ iw2 + ib2) * mean(emo) -> out col 5
// comb K layout: cue[0,768) | internal[768,896) | rw,ts,emo[896,902) | 0 pad 960
// 256 blocks x 512 thr (8 waves, 2x4). Wave: enc 64x64 (acc1 4x4) +
// imp 64x16 (acc2 4x1). 15 K-steps of 64. Double-buffered LDS, one barrier
// per K-step; loads issued post-barrier, drained by vmcnt(0) pre-barrier
// (full MFMA phase in flight).
// ---------------------------------------------------------------------------
__global__ __launch_bounds__(512) void k_encimp(
    const float* __restrict__ cue, const float* __restrict__ internal,
    const float* __restrict__ reward, const float* __restrict__ tsp,
    const float* __restrict__ emo, const unsigned short* __restrict__ W1T,
    const unsigned short* __restrict__ impW1T,
    const float* __restrict__ b1, const float* __restrict__ ib1,
    const float* __restrict__ iw2, const float* __restrict__ ib2,
    unsigned short* __restrict__ h1, float* __restrict__ out) {
  __shared__ unsigned char sm[114688];
  unsigned char* smA  = sm;            // 2 x 16384  [128 rows][128 B] swizzled
  unsigned char* smB1 = sm + 32768;    // 2 x 32768  [256 rows][128 B]
  unsigned char* smB2 = sm + 98304;    // 2 x 8192   [64 rows][128 B]

  const int t = threadIdx.x;
  const int lane = t & 63, w = t >> 6;
  const int wr = w >> 2, wc = w & 3;
  const int g = lane >> 4, c = lane & 15;
  const int row0 = blockIdx.x * 128;

  // A staging: thread -> (row srow, 16-col quarter q)
  const int srow = t >> 2, q = t & 3;
  const int abyte = srow * 128 + q * 32;
  const int aswz = (srow & 7) << 4;
  const int myrow = row0 + srow;

  f32x4 aR0, aR1, aR2, aR3;

  auto issueA = [&](int j) {
    if (j < 12) {
      const float* s = cue + (size_t)myrow * 768 + j * 64 + q * 16;
      aR0 = *(const f32x4*)(s + 0);  aR1 = *(const f32x4*)(s + 4);
      aR2 = *(const f32x4*)(s + 8);  aR3 = *(const f32x4*)(s + 12);
    } else if (j < 14) {
      const float* s = internal + (size_t)myrow * 128 + (j - 12) * 64 + q * 16;
      aR0 = *(const f32x4*)(s + 0);  aR1 = *(const f32x4*)(s + 4);
      aR2 = *(const f32x4*)(s + 8);  aR3 = *(const f32x4*)(s + 12);
    } else {
      aR0 = f32x4{0.f, 0.f, 0.f, 0.f}; aR1 = f32x4{0.f, 0.f, 0.f, 0.f};
      aR2 = f32x4{0.f, 0.f, 0.f, 0.f}; aR3 = f32x4{0.f, 0.f, 0.f, 0.f};
      if (q == 0) {
        f32x4 e4 = *(const f32x4*)(emo + (size_t)myrow * 4);
        aR0[0] = reward[myrow]; aR0[1] = tsp[myrow];
        aR0[2] = e4[0]; aR0[3] = e4[1];
        aR1[0] = e4[2]; aR1[1] = e4[3];
      }
    }
  };

  auto convWrite = [&](int buf) {
    unsigned int pk[8];
    pk[0] = (unsigned)f32_to_f16u(aR0[0]) | ((unsigned)f32_to_f16u(aR0[1]) << 16);
    pk[1] = (unsigned)f32_to_f16u(aR0[2]) | ((unsigned)f32_to_f16u(aR0[3]) << 16);
    pk[2] = (unsigned)f32_to_f16u(aR1[0]) | ((unsigned)f32_to_f16u(aR1[1]) << 16);
    pk[3] = (unsigned)f32_to_f16u(aR1[2]) | ((unsigned)f32_to_f16u(aR1[3]) << 16);
    pk[4] = (unsigned)f32_to_f16u(aR2[0]) | ((unsigned)f32_to_f16u(aR2[1]) << 16);
    pk[5] = (unsigned)f32_to_f16u(aR2[2]) | ((unsigned)f32_to_f16u(aR2[3]) << 16);
    pk[6] = (unsigned)f32_to_f16u(aR3[0]) | ((unsigned)f32_to_f16u(aR3[1]) << 16);
    pk[7] = (unsigned)f32_to_f16u(aR3[2]) | ((unsigned)f32_to_f16u(aR3[3]) << 16);
    unsigned char* base = smA + buf * 16384;
    *(uint4v*)(base + ((abyte) ^ aswz))      = uint4v{pk[0], pk[1], pk[2], pk[3]};
    *(uint4v*)(base + ((abyte + 16) ^ aswz)) = uint4v{pk[4], pk[5], pk[6], pk[7]};
  };

  auto issueB1 = [&](int j, int buf) {
#pragma unroll
    for (int i = 0; i < 4; ++i) {
      int L = i * 8192 + t * 16;
      int nl = L >> 7, x = L & 127;
      const unsigned char* gs = (const unsigned char*)W1T +
          ((size_t)nl * 768 + j * 64) * 2 + (x ^ ((nl & 7) << 4));
      gload_lds16(smB1 + buf * 32768 + i * 8192 + w * 1024, gs);
    }
  };

  auto issueB2 = [&](int j, int buf) {
    int L = t * 16;
    int nl = L >> 7, x = L & 127;
    const unsigned char* gs = (const unsigned char*)impW1T +
        (size_t)nl * 1920 + j * 128 + (x ^ ((nl & 7) << 4));
    gload_lds16(smB2 + buf * 8192 + w * 1024, gs);
  };

  f32x4 acc1[4][4];
  f32x4 acc2[4];
#pragma unroll
  for (int i = 0; i < 4; ++i) {
    acc2[i] = f32x4{0.f, 0.f, 0.f, 0.f};
#pragma unroll
    for (int j = 0; j < 4; ++j) acc1[i][j] = f32x4{0.f, 0.f, 0.f, 0.f};
  }

  // ---- pipeline prologue ----
  issueA(0); issueB1(0, 0); issueB2(0, 0);
  convWrite(0);                 // auto-waits A(0); B(0) still in flight
  VMCNT0;                       // B(0) landed in LDS
  LGKM0; SBAR;
  issueA(1); issueB1(1, 1); issueB2(1, 1);

  int p = 0;
  for (int it = 0; it < 15; ++it) {
    // ---- MFMA on buffers p (tile it) ----
    const unsigned char* Ab  = smA  + p * 16384;
    const unsigned char* B1b = smB1 + p * 32768;
    const unsigned char* B2b = smB2 + p * 8192;
#pragma unroll
    for (int ks = 0; ks < 2; ++ks) {
      half8 af[4];
#pragma unroll
      for (int mf = 0; mf < 4; ++mf) {
        int m = wr * 64 + mf * 16 + c;
        af[mf] = *(const half8*)(Ab + m * 128 + (((ks * 64) + g * 16) ^ ((m & 7) << 4)));
      }
      {
        int n2 = wc * 16 + c;
        half8 b2f = *(const half8*)(B2b + n2 * 128 + (((ks * 64) + g * 16) ^ ((n2 & 7) << 4)));
#pragma unroll
        for (int mf = 0; mf < 4; ++mf) acc2[mf] = mfma16(af[mf], b2f, acc2[mf]);
      }
      if (it < 12) {
#pragma unroll
        for (int nf = 0; nf < 4; ++nf) {
          int n = wc * 64 + nf * 16 + c;
          half8 bf = *(const half8*)(B1b + n * 128 + (((ks * 64) + g * 16) ^ ((n & 7) << 4)));
#pragma unroll
          for (int mf = 0; mf < 4; ++mf) acc1[mf][nf] = mfma16(af[mf], bf, acc1[mf][nf]);
        }
      }
    }
    // ---- stage tile it+1 A (from regs), drain tile it+1 B, barrier ----
    if (it < 14) convWrite(p ^ 1);   // auto-waits A(it+1) reg loads
    VMCNT0;                          // B(it+1) gloads landed (issued last iter)
    LGKM0; SBAR;
    // ---- issue tile it+2 into buffer p (all readers done pre-barrier) ----
    if (it + 2 <= 14) {
      issueA(it + 2);
      if (it + 2 <= 11) issueB1(it + 2, p);
      issueB2(it + 2, p);
    }
    p ^= 1;
  }

  // ---- enc1 epilogue: bias + exact gelu -> h1 f16 ----
  float bias1[4];
#pragma unroll
  for (int nf = 0; nf < 4; ++nf) bias1[nf] = b1[wc * 64 + nf * 16 + c];
#pragma unroll
  for (int mf = 0; mf < 4; ++mf)
#pragma unroll
    for (int nf = 0; nf < 4; ++nf)
#pragma unroll
      for (int r = 0; r < 4; ++r) {
        float x = acc1[mf][nf][r] + bias1[nf];
        int m = row0 + wr * 64 + mf * 16 + g * 4 + r;
        int n = wc * 64 + nf * 16 + c;
        h1[(size_t)m * 256 + n] = f32_to_f16u(gelu_exact(x));
      }

  // ---- imp epilogue: gelu * w2, reduce 16 lanes -> LDS partials -> final ----
  float b1v = ib1[wc * 16 + c];
  float w2v = iw2[wc * 16 + c];
  float* s_p = (float*)sm;  // [128][4]; safe: all LDS reads done at last SBAR
#pragma unroll
  for (int mf = 0; mf < 4; ++mf)
#pragma unroll
    for (int r = 0; r < 4; ++r) {
      float v = gelu_exact(acc2[mf][r] + b1v) * w2v;
      v += __shfl_xor(v, 1);
      v += __shfl_xor(v, 2);
      v += __shfl_xor(v, 4);
      v += __shfl_xor(v, 8);
      if (c == 0) s_p[(wr * 64 + mf * 16 + g * 4 + r) * 4 + wc] = v;
    }
  LGKM0; SBAR;
  if (t < 128) {
    float ssum = s_p[t * 4 + 0] + s_p[t * 4 + 1] + s_p[t * 4 + 2] + s_p[t * 4 + 3];
    int rowA = row0 + t;
    float z = ssum + ib2[0];
    float sig = 1.0f / (1.0f + expf(-z));
    f32x4 e4 = *(const f32x4*)(emo + (size_t)rowA * 4);
    float m4 = 0.25f * (e4[0] + e4[1] + e4[2] + e4[3]);
    out[(size_t)rowA * 6 + 5] = sig * m4;
  }
}

// ---------------------------------------------------------------------------
// enc2: enc = h1 @ W2 + b2   [32768,256]x[256,128] -> f16 [32768][128]
// ---------------------------------------------------------------------------
__global__ __launch_bounds__(256) void k_enc2(
    const unsigned short* __restrict__ h1, const unsigned short* __restrict__ W2T,
    const float* __restrict__ b2, unsigned short* __restrict__ enc) {
  __shared__ unsigned char smA[16384];
  __shared__ unsigned char smB[8192];
  const int t = threadIdx.x;
  const int lane = t & 63, w = t >> 6;
  const int wr = w >> 1, wc = w & 1;
  const int g = lane >> 4, c = lane & 15;
  const int row0 = blockIdx.x * 128;
  const int n0 = blockIdx.y * 64;

  f32x4 acc[4][2];
#pragma unroll
  for (int i = 0; i < 4; ++i)
#pragma unroll
    for (int j = 0; j < 2; ++j) acc[i][j] = f32x4{0.f, 0.f, 0.f, 0.f};

  for (int it = 0; it < 4; ++it) {
    __syncthreads();
#pragma unroll
    for (int i = 0; i < 4; ++i) {  // stage A from h1 (f16 already)
      int L = i * 4096 + t * 16;
      int rl = L >> 7, x = L & 127;
      const unsigned char* gs = (const unsigned char*)h1 +
          (size_t)(row0 + rl) * 512 + it * 128 + (x ^ ((rl & 7) << 4));
      gload_lds16(smA + i * 4096 + w * 1024, gs);
    }
#pragma unroll
    for (int i = 0; i < 2; ++i) {  // stage B from W2T
      int L = i * 4096 + t * 16;
      int nl = L >> 7, x = L & 127;
      const unsigned char* gs = (const unsigned char*)W2T +
          (size_t)(n0 + nl) * 512 + it * 128 + (x ^ ((nl & 7) << 4));
      gload_lds16(smB + i * 4096 + w * 1024, gs);
    }
    __syncthreads();
#pragma unroll
    for (int ks = 0; ks < 2; ++ks) {
      half8 af[4], bf[2];
#pragma unroll
      for (int mf = 0; mf < 4; ++mf) {
        int m = wr * 64 + mf * 16 + c;
        af[mf] = *(const half8*)(smA + m * 128 + (((ks * 64) + g * 16) ^ ((m & 7) << 4)));
      }
#pragma unroll
      for (int nf = 0; nf < 2; ++nf) {
        int n = wc * 32 + nf * 16 + c;
        bf[nf] = *(const half8*)(smB + n * 128 + (((ks * 64) + g * 16) ^ ((n & 7) << 4)));
      }
#pragma unroll
      for (int mf = 0; mf < 4; ++mf)
#pragma unroll
        for (int nf = 0; nf < 2; ++nf)
          acc[mf][nf] = mfma16(af[mf], bf[nf], acc[mf][nf]);
    }
  }
  float bias[2];
#pragma unroll
  for (int nf = 0; nf < 2; ++nf) bias[nf] = b2[n0 + wc * 32 + nf * 16 + c];
#pragma unroll
  for (int mf = 0; mf < 4; ++mf)
#pragma unroll
    for (int nf = 0; nf < 2; ++nf)
#pragma unroll
      for (int r = 0; r < 4; ++r) {
        float x = acc[mf][nf][r] + bias[nf];
        int m = row0 + wr * 64 + mf * 16 + g * 4 + r;
        int n = n0 + wc * 32 + nf * 16 + c;
        enc[(size_t)m * 128 + n] = f32_to_f16u(x);
      }
}

// ---------------------------------------------------------------------------
// sims + top5 (streaming): per block 64 rows; each wave 16 rows x 512 cols,
// processed in 4 chunks of 128 cols. Per chunk only acc[8] live; cosine ->
// monotone-u32 key -> branchless insert into running sorted top-5 (per row).
// ---------------------------------------------------------------------------
__global__ __launch_bounds__(256) void k_sims(
    const unsigned short* __restrict__ enc, const unsigned short* __restrict__ centC,
    const float* __restrict__ c_n, float* __restrict__ out) {
  __shared__ unsigned char smC[32768];  // centroid chunk [128][256 B], swizzled
  __shared__ float s_en[64];
  const int t = threadIdx.x, lane = t & 63, w = t >> 6;
  const int g = lane >> 4, c = lane & 15;
  const int row0 = blockIdx.x * 64;

  {  // row norms of enc (f16-rounded values -> consistent with num)
    int r = t >> 2, q = t & 3;
    const unsigned char* base = (const unsigned char*)enc + (size_t)(row0 + r) * 256 + q * 64;
    float s = 0.f;
#pragma unroll
    for (int j = 0; j < 4; ++j) {
      uint4v u = *(const uint4v*)(base + j * 16);
#pragma unroll
      for (int e = 0; e < 4; ++e) {
        float lo = f16u_to_f32((unsigned short)(u[e] & 0xFFFFu));
        float hi = f16u_to_f32((unsigned short)(u[e] >> 16));
        s += lo * lo + hi * hi;
      }
    }
    s += __shfl_xor(s, 1);
    s += __shfl_xor(s, 2);
    if (q == 0) s_en[r] = sqrtf(s);
  }
  __syncthreads();

  float en[4];
#pragma unroll
  for (int r = 0; r < 4; ++r) en[r] = s_en[w * 16 + g * 4 + r];

  half8 af[4];
  {
    const unsigned char* abase =
        (const unsigned char*)enc + (size_t)(row0 + w * 16 + c) * 256 + g * 16;
#pragma unroll
    for (int kk = 0; kk < 4; ++kk) af[kk] = *(const half8*)(abase + kk * 64);
  }

  unsigned int top5[4][5];
#pragma unroll
  for (int r = 0; r < 4; ++r)
#pragma unroll
    for (int s5 = 0; s5 < 5; ++s5) top5[r][s5] = 0u;

#pragma unroll
  for (int ch = 0; ch < 4; ++ch) {
    __syncthreads();
#pragma unroll
    for (int i = 0; i < 8; ++i) {
      int L = i * 4096 + t * 16;
      int nl = L >> 8, x = L & 255;
      const unsigned char* gs = (const unsigned char*)centC +
          (size_t)(ch * 128 + nl) * 256 + (x ^ ((nl & 7) << 4));
      gload_lds16(smC + i * 4096 + w * 1024, gs);
    }
    __syncthreads();

    f32x4 acc[8];
#pragma unroll
    for (int i = 0; i < 8; ++i) acc[i] = f32x4{0.f, 0.f, 0.f, 0.f};
#pragma unroll
    for (int nfc = 0; nfc < 8; ++nfc) {
      int nl = nfc * 16 + c;
      const unsigned char* bbase = smC + nl * 256;
      int swz = (nl & 7) << 4;
#pragma unroll
      for (int kk = 0; kk < 4; ++kk) {
        half8 bf = *(const half8*)(bbase + ((kk * 64 + g * 16) ^ swz));
        acc[nfc] = mfma16(af[kk], bf, acc[nfc]);
      }
    }

#pragma unroll
    for (int nfc = 0; nfc < 8; ++nfc) {
      int col = ch * 128 + nfc * 16 + c;
      float cnv = c_n[col];
#pragma unroll
      for (int r = 0; r < 4; ++r) {
        float denom = fmaxf(en[r] * cnv, 1e-8f);
        float v = acc[nfc][r] * __builtin_amdgcn_rcpf(denom);
        unsigned int u = __float_as_uint(v);
        u = (u & 0x80000000u) ? ~u : (u | 0x80000000u);
        unsigned int k = (col < 500) ? ((u & 0xFFFFFE00u) | (unsigned)col) : 0u;
        unsigned int t0 = top5[r][0], t1 = top5[r][1], t2 = top5[r][2],
                     t3 = top5[r][3], t4 = top5[r][4];
        top5[r][0] = (k > t0) ? k : t0;
        top5[r][1] = (k > t0) ? t0 : ((k > t1) ? k : t1);
        top5[r][2] = (k > t1) ? t1 : ((k > t2) ? k : t2);
        top5[r][3] = (k > t2) ? t2 : ((k > t3) ? k : t3);
        top5[r][4] = (k > t3) ? t3 : ((k > t4) ? k : t4);
      }
    }
  }

#pragma unroll
  for (int r = 0; r < 4; ++r) {
    int rowA = row0 + w * 16 + g * 4 + r;
    unsigned int h0 = top5[r][0], h1 = top5[r][1], h2 = top5[r][2],
                 h3 = top5[r][3], h4 = top5[r][4];
#pragma unroll
    for (int it5 = 0; it5 < 5; ++it5) {
      unsigned int best = h0;
#pragma unroll
      for (int s = 1; s < 16; s <<= 1) {
        unsigned int o = __shfl_xor(best, s);
        best = (o > best) ? o : best;
      }
      if (c == 0) {
        unsigned int m = best & 0xFFFFFE00u;
        unsigned int uu = (m & 0x80000000u) ? (m ^ 0x80000000u) : ~m;
        out[(size_t)rowA * 6 + it5] = __uint_as_float(uu);
      }
      bool pop = (h0 == best);
      h0 = pop ? h1 : h0;
      h1 = pop ? h2 : h1;
      h2 = pop ? h3 : h2;
      h3 = pop ? h4 : h3;
      h4 = pop ? 0u : h4;
    }
  }
}

// ---------------------------------------------------------------------------
extern "C" void kernel_launch(void* const* d_in, const int* in_sizes, int n_in,
                              void* d_out, int out_size, void* d_ws, size_t ws_size,
                              hipStream_t stream) {
  (void)in_sizes; (void)n_in; (void)out_size; (void)ws_size;
  const float* cue      = (const float*)d_in[0];
  const float* internal = (const float*)d_in[1];
  const float* reward   = (const float*)d_in[2];
  const float* tsp      = (const float*)d_in[3];
  const float* emo      = (const float*)d_in[4];
  const float* cent     = (const float*)d_in[5];
  const float* enc_w1   = (const float*)d_in[6];
  const float* enc_b1   = (const float*)d_in[7];
  const float* enc_w2   = (const float*)d_in[8];
  const float* enc_b2   = (const float*)d_in[9];
  const float* imp_w1   = (const float*)d_in[10];
  const float* imp_b1   = (const float*)d_in[11];
  const float* imp_w2   = (const float*)d_in[12];
  const float* imp_b2   = (const float*)d_in[13];
  float* out = (float*)d_out;

  unsigned char* ws = (unsigned char*)d_ws;
  unsigned short* h1     = (unsigned short*)(ws + 0);         // 32768*256*2 = 16777216
  unsigned short* enc    = (unsigned short*)(ws + 16777216);  // 32768*128*2 =  8388608
  unsigned short* W1T    = (unsigned short*)(ws + 25165824);  // 256*768*2   =   393216
  unsigned short* W2T    = (unsigned short*)(ws + 25559040);  // 128*256*2   =    65536
  unsigned short* impW1T = (unsigned short*)(ws + 25624576);  // 64*960*2    =   122880
  unsigned short* centC  = (unsigned short*)(ws + 25747456);  // 512*128*2   =   131072
  float*          c_n    = (float*)(ws + 25878528);           // 512*4       =     2048

  k_prep<<<768, 256, 0, stream>>>(enc_w1, enc_w2, imp_w1, cent, W1T, W2T, impW1T, centC, c_n);
  k_encimp<<<256, 512, 0, stream>>>(cue, internal, reward, tsp, emo, W1T, impW1T,
                                    enc_b1, imp_b1, imp_w2, imp_b2, h1, out);
  k_enc2<<<dim3(256, 2), 256, 0, stream>>>(h1, W2T, enc_b2, enc);
  k_sims<<<512, 256, 0, stream>>>(enc, centC, c_n, out);
}